// Round 1
// baseline (306.339 us; speedup 1.0000x reference)
//
#include <hip/hip_runtime.h>

#define NLAYER 4
#define BATCH  256
#define HID    1024
#define NG     4096   // 4*HID
// K total = 2048 (two 1024 segments: inp and h0_l)

typedef float f32x4 __attribute__((ext_vector_type(4)));
typedef short short8 __attribute__((ext_vector_type(8)));

__device__ __forceinline__ unsigned short f2bf(float f) {
  unsigned int u = __float_as_uint(f);
  unsigned int r = u + 0x7fffu + ((u >> 16) & 1u);  // RNE
  return (unsigned short)(r >> 16);
}

// gates[m][n] = sum_k A[m][k]*W[n][k], A = [A0|A1] (256 x 2048), W = [W0|W1] (4096 x 2048)
// 64x64 tile per block, BK=64, 256 threads = 4 waves in 2x2, wave does 32x32 (2x2 mfma tiles).
__global__ __launch_bounds__(256) void lstm_gemm(
    const float* __restrict__ A0, const float* __restrict__ A1,
    const float* __restrict__ W0, const float* __restrict__ W1,
    float* __restrict__ gates) {
  // +8 shorts pad on 64-col rows keeps ds_read_b128 16B-aligned, breaks pow2 stride
  __shared__ unsigned short lA[64 * 72];
  __shared__ unsigned short lB[64 * 72];

  const int tid = threadIdx.x;
  const int n0 = blockIdx.x * 64;   // gate-column tile
  const int m0 = blockIdx.y * 64;   // batch-row tile

  const int lane = tid & 63;
  const int w    = tid >> 6;
  const int wm   = w & 1, wn = w >> 1;
  const int lrow = lane & 15, lq = lane >> 4;

  float4 ra[4], rb[4];

  auto loadAB = [&](int kt) {
    const float* ab; const float* wb; int col;
    if (kt < 16) { ab = A0; wb = W0; col = kt * 64; }
    else         { ab = A1; wb = W1; col = (kt - 16) * 64; }
#pragma unroll
    for (int i = 0; i < 4; ++i) {
      int c = tid + (i << 8);
      int r = c >> 4;            // 0..63
      int k = (c & 15) << 2;     // 0..60
      ra[i] = *reinterpret_cast<const float4*>(ab + (size_t)(m0 + r) * 1024 + col + k);
      rb[i] = *reinterpret_cast<const float4*>(wb + (size_t)(n0 + r) * 1024 + col + k);
    }
  };

  f32x4 acc[2][2];
#pragma unroll
  for (int mt = 0; mt < 2; ++mt)
#pragma unroll
    for (int nt = 0; nt < 2; ++nt)
      acc[mt][nt] = (f32x4){0.f, 0.f, 0.f, 0.f};

  loadAB(0);
  for (int kt = 0; kt < 32; ++kt) {
    __syncthreads();  // previous tile's compute done before overwrite
#pragma unroll
    for (int i = 0; i < 4; ++i) {
      int c = tid + (i << 8);
      int r = c >> 4;
      int k = (c & 15) << 2;
      ushort4 pa, pb;
      pa.x = f2bf(ra[i].x); pa.y = f2bf(ra[i].y); pa.z = f2bf(ra[i].z); pa.w = f2bf(ra[i].w);
      pb.x = f2bf(rb[i].x); pb.y = f2bf(rb[i].y); pb.z = f2bf(rb[i].z); pb.w = f2bf(rb[i].w);
      *reinterpret_cast<ushort4*>(&lA[r * 72 + k]) = pa;
      *reinterpret_cast<ushort4*>(&lB[r * 72 + k]) = pb;
    }
    __syncthreads();
    if (kt < 31) loadAB(kt + 1);  // prefetch next tile into regs, overlaps MFMA below

#pragma unroll
    for (int kk = 0; kk < 64; kk += 32) {
      short8 af[2], bfr[2];
#pragma unroll
      for (int mt = 0; mt < 2; ++mt)
        af[mt] = *reinterpret_cast<const short8*>(
            &lA[(wm * 32 + mt * 16 + lrow) * 72 + kk + lq * 8]);
#pragma unroll
      for (int nt = 0; nt < 2; ++nt)
        bfr[nt] = *reinterpret_cast<const short8*>(
            &lB[(wn * 32 + nt * 16 + lrow) * 72 + kk + lq * 8]);
#pragma unroll
      for (int mt = 0; mt < 2; ++mt)
#pragma unroll
        for (int nt = 0; nt < 2; ++nt)
          acc[mt][nt] = __builtin_amdgcn_mfma_f32_16x16x32_bf16(
              af[mt], bfr[nt], acc[mt][nt], 0, 0, 0);
    }
  }

  // D layout: row = quad*4 + reg, col = lane&15  [m89-verified]
#pragma unroll
  for (int mt = 0; mt < 2; ++mt) {
#pragma unroll
    for (int nt = 0; nt < 2; ++nt) {
      int row = m0 + wm * 32 + mt * 16 + lq * 4;
      int col = n0 + wn * 32 + nt * 16 + lrow;
#pragma unroll
      for (int r = 0; r < 4; ++r)
        gates[(size_t)(row + r) * NG + col] = acc[mt][nt][r];
    }
  }
}

__device__ __forceinline__ float sigm(float x) { return 1.f / (1.f + __expf(-x)); }
__device__ __forceinline__ float tanh_(float x) { return 2.f / (1.f + __expf(-2.f * x)) - 1.f; }

__device__ __forceinline__ void cell1(float i_, float f_, float g_, float o_,
                                      float cprev, float& ho, float& co) {
  float cn = sigm(f_) * cprev + sigm(i_) * tanh_(g_);
  co = cn;
  ho = sigm(o_) * tanh_(cn);
}

// one thread per 4 hidden units; gate order i,f,g,o at cols h, H+h, 2H+h, 3H+h
__global__ __launch_bounds__(256) void lstm_cell(
    const float* __restrict__ gates, const float* __restrict__ bi,
    const float* __restrict__ bh, const float* __restrict__ cin,
    float* __restrict__ hout, float* __restrict__ cout) {
  int idx = blockIdx.x * 256 + threadIdx.x;  // 0..65535
  int b  = idx >> 8;
  int hq = idx & 255;  // float4 chunk within row (H/4 = 256)

  const float4* grow = reinterpret_cast<const float4*>(gates) + (size_t)b * 1024;
  const float4* bi4  = reinterpret_cast<const float4*>(bi);
  const float4* bh4  = reinterpret_cast<const float4*>(bh);

  float4 ig = grow[hq],       fg = grow[256 + hq];
  float4 gg = grow[512 + hq], og = grow[768 + hq];
  float4 i2 = bi4[hq],       f2 = bi4[256 + hq];
  float4 g2 = bi4[512 + hq], o2 = bi4[768 + hq];
  float4 i3 = bh4[hq],       f3 = bh4[256 + hq];
  float4 g3 = bh4[512 + hq], o3 = bh4[768 + hq];
  float4 c  = reinterpret_cast<const float4*>(cin)[(size_t)b * 256 + hq];

  float4 hv, cv;
  cell1(ig.x + i2.x + i3.x, fg.x + f2.x + f3.x, gg.x + g2.x + g3.x, og.x + o2.x + o3.x, c.x, hv.x, cv.x);
  cell1(ig.y + i2.y + i3.y, fg.y + f2.y + f3.y, gg.y + g2.y + g3.y, og.y + o2.y + o3.y, c.y, hv.y, cv.y);
  cell1(ig.z + i2.z + i3.z, fg.z + f2.z + f3.z, gg.z + g2.z + g3.z, og.z + o2.z + o3.z, c.z, hv.z, cv.z);
  cell1(ig.w + i2.w + i3.w, fg.w + f2.w + f3.w, gg.w + g2.w + g3.w, og.w + o2.w + o3.w, c.w, hv.w, cv.w);

  reinterpret_cast<float4*>(hout)[(size_t)b * 256 + hq] = hv;
  reinterpret_cast<float4*>(cout)[(size_t)b * 256 + hq] = cv;
}

extern "C" void kernel_launch(void* const* d_in, const int* in_sizes, int n_in,
                              void* d_out, int out_size, void* d_ws, size_t ws_size,
                              hipStream_t stream) {
  const float* x    = (const float*)d_in[0];
  const float* h0   = (const float*)d_in[1];
  const float* c0   = (const float*)d_in[2];
  const float* w_ih = (const float*)d_in[3];
  const float* w_hh = (const float*)d_in[4];
  const float* b_ih = (const float*)d_in[5];
  const float* b_hh = (const float*)d_in[6];
  float* out   = (float*)d_out;
  float* gates = (float*)d_ws;  // B*4H fp32 = 4 MB scratch, reused per layer

  const size_t BH = (size_t)BATCH * HID;  // 262144
  for (int l = 0; l < NLAYER; ++l) {
    const float* A0 = (l == 0) ? x : out + (size_t)(l - 1) * BH;  // layer input
    const float* A1 = h0 + (size_t)l * BH;                        // hidden state
    const float* W0 = w_ih + (size_t)l * (size_t)NG * 1024;
    const float* W1 = w_hh + (size_t)l * (size_t)NG * 1024;
    lstm_gemm<<<dim3(64, 4), 256, 0, stream>>>(A0, A1, W0, W1, gates);
    lstm_cell<<<dim3(256), 256, 0, stream>>>(
        gates, b_ih + (size_t)l * NG, b_hh + (size_t)l * NG,
        c0 + (size_t)l * BH,
        out + (size_t)l * BH, out + (size_t)NLAYER * BH + (size_t)l * BH);
  }
}

// Round 2
// 264.140 us; speedup vs baseline: 1.1598x; 1.1598x over previous
//
#include <hip/hip_runtime.h>

#define NLAYER 4
#define BATCH  256
#define HID    1024

typedef float f32x4 __attribute__((ext_vector_type(4)));
typedef short short8 __attribute__((ext_vector_type(8)));

// Raw barrier: LDS-only drain (lgkmcnt(0)), NO vmcnt drain -> global-load
// prefetch stays in flight across the barrier. __syncthreads() would emit
// s_waitcnt vmcnt(0) and kill the pipeline.
#define BARRIER() __asm__ __volatile__("s_waitcnt lgkmcnt(0)\ns_barrier" ::: "memory")

__device__ __forceinline__ unsigned short f2bf(float f) {
  unsigned int u = __float_as_uint(f);
  unsigned int r = u + 0x7fffu + ((u >> 16) & 1u);  // RNE
  return (unsigned short)(r >> 16);
}
__device__ __forceinline__ float sigm(float x) { return 1.f / (1.f + __expf(-x)); }
__device__ __forceinline__ float tanh_(float x) { return 2.f / (1.f + __expf(-2.f * x)) - 1.f; }

// One block = 64 batch rows x (4 gates x 16 h-cols), K=2048 ([inp|h] x [w_ih|w_hh]).
// 512 threads = 8 waves (4 m-quads x 2 col-halves), each wave one 16x32 tile.
// Double-buffered LDS, register prefetch, single raw barrier per K-iter.
// Epilogue: gates -> LDS exchange -> bias+sigmoid/tanh -> h,c (fully fused).
__global__ __launch_bounds__(512, 2) void lstm_fused(
    const float* __restrict__ A0, const float* __restrict__ A1,
    const float* __restrict__ W0, const float* __restrict__ W1,
    const float* __restrict__ bi, const float* __restrict__ bh,
    const float* __restrict__ c0l,
    float* __restrict__ hout, float* __restrict__ cout) {
  __shared__ union U {
    unsigned short stage[2][2][64 * 72];  // [buf][A/B][row*72 + k], +8 pad
    float sg[4 * 64 * 17];                // epilogue gate exchange, +1 pad
  } sm;
  __shared__ float bsum[64];              // b_ih + b_hh for this block's 64 cols

  const int tid  = threadIdx.x;
  const int h0c  = blockIdx.x * 16;  // h-column tile base
  const int m0   = blockIdx.y * 64;  // batch tile base
  const int lane = tid & 63;
  const int w    = tid >> 6;         // 0..7
  const int wm   = w & 3;            // 16-row quad
  const int wn   = w >> 1 & 0; // placeholder removed below
  const int wcol = w >> 2;           // 0..1: which 32-col half
  const int lrow = lane & 15, lq = lane >> 4;
  (void)wn;

  if (tid < 64) {
    int g = tid >> 4, hc = tid & 15;
    bsum[tid] = bi[g * 1024 + h0c + hc] + bh[g * 1024 + h0c + hc];
  }

  // staging coords: thread covers rows r0 and r0+32, 16B chunk kk0
  const int r0  = tid >> 4;          // 0..31
  const int kk0 = (tid & 15) << 2;   // 0..60
  // weight row for LDS row r: gate = r>>4, hcol = r&15
  const int wr0 = (r0 >> 4) * 1024 + h0c + (r0 & 15);
  const int r1  = r0 + 32;
  const int wr1 = (r1 >> 4) * 1024 + h0c + (r1 & 15);

  float4 ra[2], rb[2];
  auto loadAB = [&](int kt) {
    const float* ab; const float* wb; int col;
    if (kt < 16) { ab = A0; wb = W0; col = kt * 64; }
    else         { ab = A1; wb = W1; col = (kt - 16) * 64; }
    ra[0] = *reinterpret_cast<const float4*>(ab + (size_t)(m0 + r0) * 1024 + col + kk0);
    ra[1] = *reinterpret_cast<const float4*>(ab + (size_t)(m0 + r1) * 1024 + col + kk0);
    rb[0] = *reinterpret_cast<const float4*>(wb + (size_t)wr0 * 1024 + col + kk0);
    rb[1] = *reinterpret_cast<const float4*>(wb + (size_t)wr1 * 1024 + col + kk0);
  };

  f32x4 acc[2];
  acc[0] = (f32x4){0.f, 0.f, 0.f, 0.f};
  acc[1] = (f32x4){0.f, 0.f, 0.f, 0.f};

  loadAB(0);
  for (int kt = 0; kt < 32; ++kt) {
    const int buf = kt & 1;
#pragma unroll
    for (int i = 0; i < 2; ++i) {
      int r = r0 + (i << 5);
      ushort4 pa, pb;
      pa.x = f2bf(ra[i].x); pa.y = f2bf(ra[i].y); pa.z = f2bf(ra[i].z); pa.w = f2bf(ra[i].w);
      pb.x = f2bf(rb[i].x); pb.y = f2bf(rb[i].y); pb.z = f2bf(rb[i].z); pb.w = f2bf(rb[i].w);
      *reinterpret_cast<ushort4*>(&sm.stage[buf][0][r * 72 + kk0]) = pa;
      *reinterpret_cast<ushort4*>(&sm.stage[buf][1][r * 72 + kk0]) = pb;
    }
    if (kt < 31) loadAB(kt + 1);  // in flight across the raw barrier
    BARRIER();
#pragma unroll
    for (int kk = 0; kk < 64; kk += 32) {
      short8 af  = *reinterpret_cast<const short8*>(
          &sm.stage[buf][0][(wm * 16 + lrow) * 72 + kk + lq * 8]);
      short8 bf0 = *reinterpret_cast<const short8*>(
          &sm.stage[buf][1][(wcol * 32 + lrow) * 72 + kk + lq * 8]);
      short8 bf1 = *reinterpret_cast<const short8*>(
          &sm.stage[buf][1][(wcol * 32 + 16 + lrow) * 72 + kk + lq * 8]);
      acc[0] = __builtin_amdgcn_mfma_f32_16x16x32_bf16(af, bf0, acc[0], 0, 0, 0);
      acc[1] = __builtin_amdgcn_mfma_f32_16x16x32_bf16(af, bf1, acc[1], 0, 0, 0);
    }
  }

  BARRIER();  // all LDS reads done before stage -> sg overlay reuse

  // acc[nt][r]: batch row m0 + wm*16 + lq*4 + r, gate wcol*2+nt, hcol lrow
#pragma unroll
  for (int nt = 0; nt < 2; ++nt) {
    int gate = wcol * 2 + nt;
    int rowb = wm * 16 + lq * 4;
#pragma unroll
    for (int r = 0; r < 4; ++r)
      sm.sg[gate * 1088 + (rowb + r) * 17 + lrow] = acc[nt][r];
  }
  BARRIER();

  {
    int row = tid >> 3;          // 0..63
    int hp  = (tid & 7) * 2;     // 0,2,..,14
    float2 cp = *reinterpret_cast<const float2*>(c0l + (size_t)(m0 + row) * 1024 + h0c + hp);
    float cpa[2] = {cp.x, cp.y};
    float hva[2], cva[2];
#pragma unroll
    for (int e = 0; e < 2; ++e) {
      int hc = hp + e;
      float gi = sm.sg[0 * 1088 + row * 17 + hc] + bsum[0  + hc];
      float gf = sm.sg[1 * 1088 + row * 17 + hc] + bsum[16 + hc];
      float gg = sm.sg[2 * 1088 + row * 17 + hc] + bsum[32 + hc];
      float go = sm.sg[3 * 1088 + row * 17 + hc] + bsum[48 + hc];
      float cn = sigm(gf) * cpa[e] + sigm(gi) * tanh_(gg);
      cva[e] = cn;
      hva[e] = sigm(go) * tanh_(cn);
    }
    float2 hv; hv.x = hva[0]; hv.y = hva[1];
    float2 cv; cv.x = cva[0]; cv.y = cva[1];
    *reinterpret_cast<float2*>(hout + (size_t)(m0 + row) * 1024 + h0c + hp) = hv;
    *reinterpret_cast<float2*>(cout + (size_t)(m0 + row) * 1024 + h0c + hp) = cv;
  }
}

extern "C" void kernel_launch(void* const* d_in, const int* in_sizes, int n_in,
                              void* d_out, int out_size, void* d_ws, size_t ws_size,
                              hipStream_t stream) {
  const float* x    = (const float*)d_in[0];
  const float* h0   = (const float*)d_in[1];
  const float* c0   = (const float*)d_in[2];
  const float* w_ih = (const float*)d_in[3];
  const float* w_hh = (const float*)d_in[4];
  const float* b_ih = (const float*)d_in[5];
  const float* b_hh = (const float*)d_in[6];
  float* out = (float*)d_out;

  const size_t BH = (size_t)BATCH * HID;       // 262144
  const size_t WL = (size_t)4 * HID * HID;     // 4M floats per weight matrix

  for (int l = 0; l < NLAYER; ++l) {
    const float* A0 = (l == 0) ? x : out + (size_t)(l - 1) * BH;
    lstm_fused<<<dim3(64, 4), 512, 0, stream>>>(
        A0, h0 + (size_t)l * BH,
        w_ih + (size_t)l * WL, w_hh + (size_t)l * WL,
        b_ih + (size_t)l * 4096, b_hh + (size_t)l * 4096,
        c0 + (size_t)l * BH,
        out + (size_t)l * BH, out + (size_t)NLAYER * BH + (size_t)l * BH);
  }
}

// Round 3
// 263.577 us; speedup vs baseline: 1.1622x; 1.0021x over previous
//
#include <hip/hip_runtime.h>

#define NLAYER 4
#define BATCH  256
#define HID    1024

typedef float f32x4 __attribute__((ext_vector_type(4)));
typedef short short8 __attribute__((ext_vector_type(8)));

// LDS-only drain: global-load prefetch stays in flight across the barrier.
#define BARRIER() __asm__ __volatile__("s_waitcnt lgkmcnt(0)\ns_barrier" ::: "memory")

__device__ __forceinline__ unsigned short f2bf(float f) {
  unsigned int u = __float_as_uint(f);
  unsigned int r = u + 0x7fffu + ((u >> 16) & 1u);  // RNE
  return (unsigned short)(r >> 16);
}
__device__ __forceinline__ float sigm(float x) { return 1.f / (1.f + __expf(-x)); }
__device__ __forceinline__ float tanh_(float x) { return 2.f / (1.f + __expf(-2.f * x)) - 1.f; }

// Swizzled LDS addressing (shorts). Row = 64 shorts = 8x 16B chunks; chunk
// index XORed with row&7 -> b128 fragment reads land 2-way max (free),
// staging writes spread 4/bank even. No padding, b128 alignment preserved.
__device__ __forceinline__ int lds_w(int r, int kk0) {   // write: 8B at k-offset kk0
  return r * 64 + (((kk0 >> 3) ^ (r & 7)) << 3) + (kk0 & 7);
}
__device__ __forceinline__ int lds_r(int row, int c) {   // read: 16B chunk c
  return row * 64 + ((c ^ (row & 7)) << 3);
}

// One block: 64 batch rows x (4 gates x 16 h-cols), K=2048 = [inp|h]x[w_ih|w_hh].
// 512 threads = 8 waves (4 row-quads x 2 col-halves), wave = 16x32 (2 acc tiles).
// Depth-3 rotating register prefetch; raw lgkm-only barrier; fused LSTM epilogue.
__global__ __launch_bounds__(512, 2) void lstm_fused(
    const float* __restrict__ A0, const float* __restrict__ A1,
    const float* __restrict__ W0, const float* __restrict__ W1,
    const float* __restrict__ bi, const float* __restrict__ bh,
    const float* __restrict__ c0l,
    float* __restrict__ hout, float* __restrict__ cout) {
  __shared__ union U {
    unsigned short stage[2][2][64 * 64];  // [buf][A/B][swizzled]
    float sg[4 * 64 * 17];                // epilogue gate exchange (+1 pad)
  } sm;
  __shared__ float bsum[64];

  const int tid  = threadIdx.x;
  const int h0c  = blockIdx.x * 16;
  const int m0   = blockIdx.y * 64;
  const int lane = tid & 63;
  const int w    = tid >> 6;
  const int wm   = w & 3;            // 16-row quad
  const int wcol = w >> 2;           // 32-col half
  const int lrow = lane & 15, lq = lane >> 4;

  if (tid < 64) {
    int g = tid >> 4, hc = tid & 15;
    bsum[tid] = bi[g * 1024 + h0c + hc] + bh[g * 1024 + h0c + hc];
  }

  // staging: thread covers LDS rows r0, r0+32 at 16B k-chunk kk0
  const int r0  = tid >> 4;          // 0..31
  const int kk0 = (tid & 15) << 2;   // 0..60 (floats)
  const int wr0 = (r0 >> 4) * 1024 + h0c + (r0 & 15);  // W row for LDS row r0

  const float* pA0 = A0 + (size_t)(m0 + r0) * 1024 + kk0;
  const float* pA1 = A1 + (size_t)(m0 + r0) * 1024 + kk0;
  const float* pW0 = W0 + (size_t)wr0 * 1024 + kk0;
  const float* pW1 = W1 + (size_t)wr0 * 1024 + kk0;

  // epilogue c prefetch (hot before the long loop)
  const int erow = tid >> 3;         // 0..63
  const int ehp  = (tid & 7) * 2;    // 0..14
  float2 cp = *reinterpret_cast<const float2*>(
      c0l + (size_t)(m0 + erow) * 1024 + h0c + ehp);

  float4 ra[4][2], rb[4][2];
  auto loadAB = [&](int kt, int s) {
    const float* pa = (kt < 16 ? pA0 : pA1) + (kt & 15) * 64;
    const float* pb = (kt < 16 ? pW0 : pW1) + (kt & 15) * 64;
    ra[s][0] = *reinterpret_cast<const float4*>(pa);
    ra[s][1] = *reinterpret_cast<const float4*>(pa + 32 * 1024);
    rb[s][0] = *reinterpret_cast<const float4*>(pb);
    rb[s][1] = *reinterpret_cast<const float4*>(pb + 2048 * 1024);
  };

  f32x4 acc[2];
  acc[0] = (f32x4){0.f, 0.f, 0.f, 0.f};
  acc[1] = (f32x4){0.f, 0.f, 0.f, 0.f};

  loadAB(0, 0); loadAB(1, 1); loadAB(2, 2);

  for (int kt4 = 0; kt4 < 32; kt4 += 4) {
#pragma unroll
    for (int ks = 0; ks < 4; ++ks) {
      const int kt  = kt4 + ks;
      const int buf = ks & 1;  // kt4 even -> buf = kt&1
      // stage group kt (compiler waits vmcnt on this group only: vmcnt(8))
#pragma unroll
      for (int i = 0; i < 2; ++i) {
        int r = r0 + (i << 5);
        ushort4 pa, pb;
        pa.x = f2bf(ra[ks][i].x); pa.y = f2bf(ra[ks][i].y);
        pa.z = f2bf(ra[ks][i].z); pa.w = f2bf(ra[ks][i].w);
        pb.x = f2bf(rb[ks][i].x); pb.y = f2bf(rb[ks][i].y);
        pb.z = f2bf(rb[ks][i].z); pb.w = f2bf(rb[ks][i].w);
        *reinterpret_cast<ushort4*>(&sm.stage[buf][0][lds_w(r, kk0)]) = pa;
        *reinterpret_cast<ushort4*>(&sm.stage[buf][1][lds_w(r, kk0)]) = pb;
      }
      if (kt < 29) loadAB(kt + 3, (ks + 3) & 3);  // stays in flight across barrier
      BARRIER();
#pragma unroll
      for (int kk = 0; kk < 64; kk += 32) {
        const int cb = kk >> 3;  // base chunk (0 or 4)
        short8 af = *reinterpret_cast<const short8*>(
            &sm.stage[buf][0][lds_r(wm * 16 + lrow, cb + lq)]);
        short8 bf0 = *reinterpret_cast<const short8*>(
            &sm.stage[buf][1][lds_r(wcol * 32 + lrow, cb + lq)]);
        short8 bf1 = *reinterpret_cast<const short8*>(
            &sm.stage[buf][1][lds_r(wcol * 32 + 16 + lrow, cb + lq)]);
        acc[0] = __builtin_amdgcn_mfma_f32_16x16x32_bf16(af, bf0, acc[0], 0, 0, 0);
        acc[1] = __builtin_amdgcn_mfma_f32_16x16x32_bf16(af, bf1, acc[1], 0, 0, 0);
      }
    }
  }

  BARRIER();  // all stage reads done before sg overlay reuse

  // acc[nt][r]: row m0 + wm*16 + lq*4 + r, gate wcol*2+nt, hcol lrow
#pragma unroll
  for (int nt = 0; nt < 2; ++nt) {
    int gate = wcol * 2 + nt;
    int rowb = wm * 16 + lq * 4;
#pragma unroll
    for (int r = 0; r < 4; ++r)
      sm.sg[gate * 1088 + (rowb + r) * 17 + lrow] = acc[nt][r];
  }
  BARRIER();

  {
    float cpa[2] = {cp.x, cp.y};
    float hva[2], cva[2];
#pragma unroll
    for (int e = 0; e < 2; ++e) {
      int hc = ehp + e;
      float gi = sm.sg[0 * 1088 + erow * 17 + hc] + bsum[0  + hc];
      float gf = sm.sg[1 * 1088 + erow * 17 + hc] + bsum[16 + hc];
      float gg = sm.sg[2 * 1088 + erow * 17 + hc] + bsum[32 + hc];
      float go = sm.sg[3 * 1088 + erow * 17 + hc] + bsum[48 + hc];
      float cn = sigm(gf) * cpa[e] + sigm(gi) * tanh_(gg);
      cva[e] = cn;
      hva[e] = sigm(go) * tanh_(cn);
    }
    float2 hv; hv.x = hva[0]; hv.y = hva[1];
    float2 cv; cv.x = cva[0]; cv.y = cva[1];
    *reinterpret_cast<float2*>(hout + (size_t)(m0 + erow) * 1024 + h0c + ehp) = hv;
    *reinterpret_cast<float2*>(cout + (size_t)(m0 + erow) * 1024 + h0c + ehp) = cv;
  }
}

extern "C" void kernel_launch(void* const* d_in, const int* in_sizes, int n_in,
                              void* d_out, int out_size, void* d_ws, size_t ws_size,
                              hipStream_t stream) {
  const float* x    = (const float*)d_in[0];
  const float* h0   = (const float*)d_in[1];
  const float* c0   = (const float*)d_in[2];
  const float* w_ih = (const float*)d_in[3];
  const float* w_hh = (const float*)d_in[4];
  const float* b_ih = (const float*)d_in[5];
  const float* b_hh = (const float*)d_in[6];
  float* out = (float*)d_out;

  const size_t BH = (size_t)BATCH * HID;
  const size_t WL = (size_t)4 * HID * HID;

  for (int l = 0; l < NLAYER; ++l) {
    const float* A0 = (l == 0) ? x : out + (size_t)(l - 1) * BH;
    lstm_fused<<<dim3(64, 4), 512, 0, stream>>>(
        A0, h0 + (size_t)l * BH,
        w_ih + (size_t)l * WL, w_hh + (size_t)l * WL,
        b_ih + (size_t)l * 4096, b_hh + (size_t)l * 4096,
        c0 + (size_t)l * BH,
        out + (size_t)l * BH, out + (size_t)NLAYER * BH + (size_t)l * BH);
  }
}

// Round 4
// 224.602 us; speedup vs baseline: 1.3639x; 1.1735x over previous
//
#include <hip/hip_runtime.h>

#define NLAYER 4
#define BATCH  256
#define HID    1024

typedef float f32x4 __attribute__((ext_vector_type(4)));
typedef short short8 __attribute__((ext_vector_type(8)));
typedef unsigned short ushort_t;

// Raw wave-level sync primitives. No "memory" clobber on BAR/WAITV: keeps the
// compiler from draining the DMA queue; ordering vs DMA/ds_read is maintained
// because all of those are side-effecting (builtin / asm volatile).
#define BAR()     asm volatile("s_barrier")
#define WAITV(n)  asm volatile("s_waitcnt vmcnt(" #n ")")
#define DSR(d, a) asm volatile("ds_read_b128 %0, %1" : "=v"(d) : "v"(a))
#define LGKM0_TIE6(a,b,c,d,e,f) \
  asm volatile("s_waitcnt lgkmcnt(0)" : "+v"(a),"+v"(b),"+v"(c),"+v"(d),"+v"(e),"+v"(f))
#define FULLBAR() asm volatile("s_waitcnt lgkmcnt(0)\ns_barrier" ::: "memory")

__device__ __forceinline__ unsigned short f2bf(float f) {
  unsigned int u = __float_as_uint(f);
  unsigned int r = u + 0x7fffu + ((u >> 16) & 1u);  // RNE
  return (unsigned short)(r >> 16);
}
__device__ __forceinline__ float sigm(float x) { return 1.f / (1.f + __expf(-x)); }
__device__ __forceinline__ float tanh_(float x) { return 2.f / (1.f + __expf(-2.f * x)) - 1.f; }

// global (per-lane addr) -> LDS (wave-uniform base + lane*16), 16B per lane
__device__ __forceinline__ void dma16(const void* g, void* l) {
  __builtin_amdgcn_global_load_lds(
      (const __attribute__((address_space(1))) unsigned int*)g,
      (__attribute__((address_space(3))) unsigned int*)l, 16, 0, 0);
}

// Packed tile format (per 64x64 tile = 8KB = 8 groups of 1KB):
//   logical (r 0..63, c 0..7 [16B k-chunks]) stored at group g=r>>3,
//   lane i = (r&7)*8 + ((c^r)&7). DMA deposits lane-linear -> LDS image has
//   bank-group (addr/16 mod 8) = c^(r&7): fragment b128 reads conflict-free.

// ---- pack weights: [l][nb][kt 0..31][g][lane] ; kt<16 => w_ih, else w_hh ----
__global__ __launch_bounds__(256) void pack_w(const float* __restrict__ w_ih,
                                              const float* __restrict__ w_hh,
                                              ushort_t* __restrict__ wpk) {
  int tid = blockIdx.x * 256 + threadIdx.x;  // 0..4194303
  int lane = tid & 63;
  int kt   = (tid >> 9) & 31;
  int nb   = (tid >> 14) & 63;
  int l    = tid >> 20;
  int g    = (tid >> 6) & 7;
  int r = g * 8 + (lane >> 3);
  int c = (lane & 7) ^ (lane >> 3);
  int wrow = (r >> 4) * 1024 + nb * 16 + (r & 15);
  const float* src = (kt < 16 ? w_ih : w_hh) + (size_t)l * 4194304
                   + (size_t)wrow * 1024 + (kt & 15) * 64 + c * 8;
  float4 a = *(const float4*)src, b = *(const float4*)(src + 4);
  short8 pk;
  pk[0] = (short)f2bf(a.x); pk[1] = (short)f2bf(a.y);
  pk[2] = (short)f2bf(a.z); pk[3] = (short)f2bf(a.w);
  pk[4] = (short)f2bf(b.x); pk[5] = (short)f2bf(b.y);
  pk[6] = (short)f2bf(b.z); pk[7] = (short)f2bf(b.w);
  *(short8*)(wpk + (size_t)tid * 8) = pk;  // tid*8 == l,nb,kt,g,lane packed offset
}

// ---- pack A: layer0 kt0..15 from x; all layers kt16..31 from h0[l] ----
__global__ __launch_bounds__(256) void pack_a(const float* __restrict__ x,
                                              const float* __restrict__ h0,
                                              ushort_t* __restrict__ apk) {
  int t = blockIdx.x * 256 + threadIdx.x;  // 0..163839
  int lane = t & 63;
  int r8 = lane >> 3;
  int c = (lane & 7) ^ r8;
  const float* src;
  ushort_t* dst;
  if (t < 32768) {
    int g = (t >> 6) & 7, kt = (t >> 9) & 15, mb = t >> 13;  // mb 0..3
    int m = mb * 64 + g * 8 + r8;
    src = x + (size_t)m * 1024 + kt * 64 + c * 8;
    dst = apk + (size_t)mb * 131072 + (size_t)kt * 4096 + g * 512 + lane * 8;
  } else {
    int u = t - 32768;
    int g = (u >> 6) & 7, kt16 = (u >> 9) & 15, mb = (u >> 13) & 3, l = u >> 15;
    int m = mb * 64 + g * 8 + r8;
    src = h0 + (size_t)l * 262144 + (size_t)m * 1024 + kt16 * 64 + c * 8;
    dst = apk + (size_t)l * 524288 + (size_t)mb * 131072
        + (size_t)(16 + kt16) * 4096 + g * 512 + lane * 8;
  }
  float4 a = *(const float4*)src, b = *(const float4*)(src + 4);
  short8 pk;
  pk[0] = (short)f2bf(a.x); pk[1] = (short)f2bf(a.y);
  pk[2] = (short)f2bf(a.z); pk[3] = (short)f2bf(a.w);
  pk[4] = (short)f2bf(b.x); pk[5] = (short)f2bf(b.y);
  pk[6] = (short)f2bf(b.z); pk[7] = (short)f2bf(b.w);
  *(short8*)dst = pk;
}

// ---- fused layer: DMA-staged bf16 GEMM (64x64 tile, BK=64, quad-buffered,
// depth-3 prefetch, hand vmcnt) + LSTM cell epilogue + packed-h for next layer.
__global__ __launch_bounds__(512) void lstm_fused(
    const ushort_t* __restrict__ apk, const ushort_t* __restrict__ wpk,
    const float* __restrict__ bi, const float* __restrict__ bh,
    const float* __restrict__ c0l,
    float* __restrict__ hout, float* __restrict__ cout,
    ushort_t* __restrict__ apk_next) {
  __shared__ union U {
    ushort_t stage[4][2][4096];  // [buf][A=0/B=1][packed 8KB tile]
    float sg[4 * 64 * 17];       // epilogue gate exchange (+1 pad)
  } sm;
  __shared__ float bsum[64];

  const int tid = threadIdx.x;
  const int nb = blockIdx.x;   // 0..63 -> 16 h-cols x 4 gates
  const int mb = blockIdx.y;   // 0..3  -> 64 batch rows
  const int h0c = nb * 16;
  const int m0 = mb * 64;
  const int lane = tid & 63;
  const int w = tid >> 6;            // 0..7
  const int wm = w & 3, wcol = w >> 2;
  const int lrow = lane & 15, lq = lane >> 4;

  if (tid < 64) {
    int g = tid >> 4, hc = tid & 15;
    bsum[tid] = bi[g * 1024 + h0c + hc] + bh[g * 1024 + h0c + hc];
  }
  const int erow = tid >> 3, ehp = (tid & 7) * 2;
  float2 cp = *(const float2*)(c0l + (size_t)(m0 + erow) * 1024 + h0c + ehp);

  // DMA sources: wave w deposits group w of A and B tiles (1KB each)
  const char* srcA = (const char*)(apk + (size_t)mb * 131072 + w * 512 + lane * 8);
  const char* srcB = (const char*)(wpk + (size_t)nb * 131072 + w * 512 + lane * 8);

  // fragment LDS byte addresses (verified 16x16x32 layouts from rounds 1-3)
  unsigned smb = (unsigned)(uintptr_t)(__attribute__((address_space(3))) void*)&sm;
  const int rA = wm * 16 + lrow;
  const int rB0 = wcol * 32 + lrow, rB1 = rB0 + 16;
#define SWZ(r, c) (((r) >> 3) * 64 + ((r) & 7) * 8 + (((c) ^ (r)) & 7))
  unsigned oA0 = smb + SWZ(rA, lq) * 16,         oA1 = smb + SWZ(rA, 4 + lq) * 16;
  unsigned oB00 = smb + 8192 + SWZ(rB0, lq) * 16, oB01 = smb + 8192 + SWZ(rB0, 4 + lq) * 16;
  unsigned oB10 = smb + 8192 + SWZ(rB1, lq) * 16, oB11 = smb + 8192 + SWZ(rB1, 4 + lq) * 16;
#undef SWZ

  f32x4 acc0 = {0.f, 0.f, 0.f, 0.f}, acc1 = {0.f, 0.f, 0.f, 0.f};

  // prologue: tiles 0,1,2 in flight
#pragma unroll
  for (int t = 0; t < 3; ++t) {
    dma16(srcA, &sm.stage[t][0][w * 512]);
    dma16(srcB, &sm.stage[t][1][w * 512]);
    srcA += 8192; srcB += 8192;
  }
  WAITV(4);  // tile 0 landed (self)

  for (int kt = 0; kt < 32; ++kt) {
    BAR();  // all waves: tile kt landed; all reads of tile kt-1 done (lgkm tie)
    if (kt <= 28) {
      int b3 = (kt + 3) & 3;  // == (kt-1)&3: that tile's reads completed pre-BAR
      dma16(srcA, &sm.stage[b3][0][w * 512]);
      dma16(srcB, &sm.stage[b3][1][w * 512]);
      srcA += 8192; srcB += 8192;
    }
    unsigned boff = (unsigned)(kt & 3) * 16384u;
    short8 af0, af1, b00, b01, b10, b11;
    DSR(af0, oA0 + boff); DSR(b00, oB00 + boff); DSR(b10, oB10 + boff);
    DSR(af1, oA1 + boff); DSR(b01, oB01 + boff); DSR(b11, oB11 + boff);
    LGKM0_TIE6(af0, af1, b00, b01, b10, b11);
    acc0 = __builtin_amdgcn_mfma_f32_16x16x32_bf16(af0, b00, acc0, 0, 0, 0);
    acc1 = __builtin_amdgcn_mfma_f32_16x16x32_bf16(af0, b10, acc1, 0, 0, 0);
    acc0 = __builtin_amdgcn_mfma_f32_16x16x32_bf16(af1, b01, acc0, 0, 0, 0);
    acc1 = __builtin_amdgcn_mfma_f32_16x16x32_bf16(af1, b11, acc1, 0, 0, 0);
    if (kt <= 28)      { WAITV(4); }  // tile kt+1 landed
    else if (kt == 29) { WAITV(2); }
    else if (kt == 30) { WAITV(0); }
  }

  FULLBAR();  // loop done, vmcnt=0; safe to overlay sg over stage

  // acc layout (verified): row = m0 + wm*16 + lq*4 + r, gate = wcol*2+nt, hcol = lrow
#pragma unroll
  for (int nt = 0; nt < 2; ++nt) {
    int gate = wcol * 2 + nt;
    int rowb = wm * 16 + lq * 4;
    const f32x4& a = nt ? acc1 : acc0;
#pragma unroll
    for (int r = 0; r < 4; ++r)
      sm.sg[gate * 1088 + (rowb + r) * 17 + lrow] = a[r];
  }
  FULLBAR();

  {
    float cpa[2] = {cp.x, cp.y};
    float hva[2], cva[2];
#pragma unroll
    for (int e = 0; e < 2; ++e) {
      int hc = ehp + e;
      float gi = sm.sg[0 * 1088 + erow * 17 + hc] + bsum[0  + hc];
      float gf = sm.sg[1 * 1088 + erow * 17 + hc] + bsum[16 + hc];
      float gg = sm.sg[2 * 1088 + erow * 17 + hc] + bsum[32 + hc];
      float go = sm.sg[3 * 1088 + erow * 17 + hc] + bsum[48 + hc];
      float cn = sigm(gf) * cpa[e] + sigm(gi) * tanh_(gg);
      cva[e] = cn;
      hva[e] = sigm(go) * tanh_(cn);
    }
    float2 hv; hv.x = hva[0]; hv.y = hva[1];
    float2 cv; cv.x = cva[0]; cv.y = cva[1];
    *(float2*)(hout + (size_t)(m0 + erow) * 1024 + h0c + ehp) = hv;
    *(float2*)(cout + (size_t)(m0 + erow) * 1024 + h0c + ehp) = cv;
    if (apk_next) {  // packed bf16 h for next layer's A-DMA (kt = k>>6 in 0..15)
      int g = erow >> 3;
#pragma unroll
      for (int e = 0; e < 2; ++e) {
        int k = h0c + ehp + e;
        int cc = (k >> 3) & 7, j = k & 7;
        int i = (erow & 7) * 8 + ((cc ^ erow) & 7);
        apk_next[(size_t)mb * 131072 + (size_t)(k >> 6) * 4096 + g * 512 + i * 8 + j] =
            f2bf(hva[e]);
      }
    }
  }
}

extern "C" void kernel_launch(void* const* d_in, const int* in_sizes, int n_in,
                              void* d_out, int out_size, void* d_ws, size_t ws_size,
                              hipStream_t stream) {
  const float* x    = (const float*)d_in[0];
  const float* h0   = (const float*)d_in[1];
  const float* c0   = (const float*)d_in[2];
  const float* w_ih = (const float*)d_in[3];
  const float* w_hh = (const float*)d_in[4];
  const float* b_ih = (const float*)d_in[5];
  const float* b_hh = (const float*)d_in[6];
  float* out = (float*)d_out;

  ushort_t* Wpk = (ushort_t*)d_ws;              // 4 layers x 16 MB
  ushort_t* Apk = Wpk + (size_t)4 * 8388608;    // 4 layers x 1 MB

  pack_w<<<16384, 256, 0, stream>>>(w_ih, w_hh, Wpk);
  pack_a<<<640, 256, 0, stream>>>(x, h0, Apk);

  const size_t BH = (size_t)BATCH * HID;
  for (int l = 0; l < NLAYER; ++l) {
    lstm_fused<<<dim3(64, 4), 512, 0, stream>>>(
        Apk + (size_t)l * 524288, Wpk + (size_t)l * 8388608,
        b_ih + (size_t)l * 4096, b_hh + (size_t)l * 4096,
        c0 + (size_t)l * BH,
        out + (size_t)l * BH, out + (size_t)NLAYER * BH + (size_t)l * BH,
        (l < NLAYER - 1) ? Apk + (size_t)(l + 1) * 524288 : (ushort_t*)nullptr);
  }
}

// Round 5
// 220.008 us; speedup vs baseline: 1.3924x; 1.0209x over previous
//
#include <hip/hip_runtime.h>

#define NLAYER 4
#define BATCH  256
#define HID    1024

typedef float f32x4 __attribute__((ext_vector_type(4)));
typedef short short8 __attribute__((ext_vector_type(8)));
typedef unsigned short ushort_t;
typedef unsigned long long u64;

// Raw sync primitives (round-4 proven discipline). All counted VM ops (DMA
// builtin + GLD16 asm) and WAITV/BAR are volatile -> mutual program order.
#define BAR()     asm volatile("s_barrier")
#define WAITV(n)  asm volatile("s_waitcnt vmcnt(" #n ")")
#define WAITV_TIE2(n, x, y) \
  asm volatile("s_waitcnt vmcnt(" #n ")" : "+v"(x), "+v"(y))
#define DSR(d, a) asm volatile("ds_read_b128 %0, %1" : "=v"(d) : "v"(a))
#define LGKM0_TIE4(a,b,c,d) \
  asm volatile("s_waitcnt lgkmcnt(0)" : "+v"(a),"+v"(b),"+v"(c),"+v"(d))
#define FULLBAR() asm volatile("s_waitcnt vmcnt(0) lgkmcnt(0)\ns_barrier" ::: "memory")
#define GLD16(d, a) asm volatile("global_load_dwordx4 %0, %1, off" : "=v"(d) : "v"(a))

__device__ __forceinline__ unsigned short f2bf(float f) {
  unsigned int u = __float_as_uint(f);
  unsigned int r = u + 0x7fffu + ((u >> 16) & 1u);  // RNE
  return (unsigned short)(r >> 16);
}
__device__ __forceinline__ float sigm(float x) { return 1.f / (1.f + __expf(-x)); }
__device__ __forceinline__ float tanh_(float x) { return 2.f / (1.f + __expf(-2.f * x)) - 1.f; }

__device__ __forceinline__ void dma16(const void* g, void* l) {
  __builtin_amdgcn_global_load_lds(
      (const __attribute__((address_space(1))) unsigned int*)g,
      (__attribute__((address_space(3))) unsigned int*)l, 16, 0, 0);
}

// Packed tile format (64x64 tile = 8KB): logical (r 0..63, c 0..7 16B-chunks)
// at chunk = (r>>3)*64 + (r&7)*8 + ((c^r)&7). Same as rounds 3-4.

// ---- pack_w v2: wave reads ONE 4KB weight row linearly; writes scattered in
// 128B segments to the packed layout. Thread: 16 consecutive floats -> two
// adjacent 16B packed chunks (iB = iA^1). Output layout identical to v1. ----
__global__ __launch_bounds__(256) void pack_w(const float* __restrict__ w_ih,
                                              const float* __restrict__ w_hh,
                                              ushort_t* __restrict__ wpk) {
  int t   = blockIdx.x * 256 + threadIdx.x;  // 0..2097151
  int j16 = t & 63;                          // 16-float chunk within row
  int m   = t >> 6;                          // global row 0..32767
  int l   = m >> 13;
  int sel = (m >> 12) & 1;                   // 0: w_ih, 1: w_hh
  int row = m & 4095;
  const float* src = (sel ? w_hh : w_ih) + (size_t)l * 4194304
                   + (size_t)row * 1024 + j16 * 16;
  float4 v0 = ((const float4*)src)[0], v1 = ((const float4*)src)[1];
  float4 v2 = ((const float4*)src)[2], v3 = ((const float4*)src)[3];

  int gate = row >> 10, nb = (row & 1023) >> 4, rlow = row & 15;
  int r  = gate * 16 + rlow;
  int g  = r >> 3;
  int kt = sel * 16 + (j16 >> 2);
  int cA = (j16 & 3) * 2;
  int iA = (r & 7) * 8 + ((cA ^ r) & 7);
  int iB = iA ^ 1;                           // c+1 flips xor bit0 (cA even)
  size_t base = ((size_t)(l * 64 + nb) * 32 + kt) * 4096 + g * 512;

  short8 pA, pB;
  pA[0]=f2bf(v0.x); pA[1]=f2bf(v0.y); pA[2]=f2bf(v0.z); pA[3]=f2bf(v0.w);
  pA[4]=f2bf(v1.x); pA[5]=f2bf(v1.y); pA[6]=f2bf(v1.z); pA[7]=f2bf(v1.w);
  pB[0]=f2bf(v2.x); pB[1]=f2bf(v2.y); pB[2]=f2bf(v2.z); pB[3]=f2bf(v2.w);
  pB[4]=f2bf(v3.x); pB[5]=f2bf(v3.y); pB[6]=f2bf(v3.z); pB[7]=f2bf(v3.w);
  *(short8*)(wpk + base + iA * 8) = pA;
  *(short8*)(wpk + base + iB * 8) = pB;
}

// ---- pack A (unchanged layout): layer0 kt0..15 from x; kt16..31 from h0[l] ----
__global__ __launch_bounds__(256) void pack_a(const float* __restrict__ x,
                                              const float* __restrict__ h0,
                                              ushort_t* __restrict__ apk) {
  int t = blockIdx.x * 256 + threadIdx.x;  // 0..163839
  int lane = t & 63;
  int r8 = lane >> 3;
  int c = (lane & 7) ^ r8;
  const float* src;
  ushort_t* dst;
  if (t < 32768) {
    int g = (t >> 6) & 7, kt = (t >> 9) & 15, mb = t >> 13;
    int m = mb * 64 + g * 8 + r8;
    src = x + (size_t)m * 1024 + kt * 64 + c * 8;
    dst = apk + (size_t)mb * 131072 + (size_t)kt * 4096 + g * 512 + lane * 8;
  } else {
    int u = t - 32768;
    int g = (u >> 6) & 7, kt16 = (u >> 9) & 15, mb = (u >> 13) & 3, l = u >> 15;
    int m = mb * 64 + g * 8 + r8;
    src = h0 + (size_t)l * 262144 + (size_t)m * 1024 + kt16 * 64 + c * 8;
    dst = apk + (size_t)l * 524288 + (size_t)mb * 131072
        + (size_t)(16 + kt16) * 4096 + g * 512 + lane * 8;
  }
  float4 a = *(const float4*)src, b = *(const float4*)(src + 4);
  short8 pk;
  pk[0] = (short)f2bf(a.x); pk[1] = (short)f2bf(a.y);
  pk[2] = (short)f2bf(a.z); pk[3] = (short)f2bf(a.w);
  pk[4] = (short)f2bf(b.x); pk[5] = (short)f2bf(b.y);
  pk[6] = (short)f2bf(b.z); pk[7] = (short)f2bf(b.w);
  *(short8*)dst = pk;
}

// ---- fused layer GEMM v2: B via DMA->LDS (quad-buffer, 8KB tiles), A-frags
// gathered direct from L2 (4 rotating reg slots, 3 ahead), exact vmcnt
// counting: per iter issue [D(kt+3), A(kt+3)x2] -> pre-BAR vmcnt(8) = D(kt)
// landed (self), post-issue vmcnt(9) = A(kt) in regs. LSTM cell epilogue. ----
__global__ __launch_bounds__(512) void lstm_fused(
    const ushort_t* __restrict__ apk, const ushort_t* __restrict__ wpk,
    const float* __restrict__ bi, const float* __restrict__ bh,
    const float* __restrict__ c0l,
    float* __restrict__ hout, float* __restrict__ cout,
    ushort_t* __restrict__ apk_next) {
  __shared__ union U {
    ushort_t stage[4][4096];   // 4 x 8KB B tiles
    float sg[4 * 64 * 17];     // epilogue gate exchange (17.4KB, fits)
  } sm;

  const int tid = threadIdx.x;
  const int nb = blockIdx.x;   // 0..63
  const int mb = blockIdx.y;   // 0..3
  const int h0c = nb * 16;
  const int m0 = mb * 64;
  const int lane = tid & 63;
  const int w = tid >> 6;
  const int wm = w & 3, wcol = w >> 2;
  const int lrow = lane & 15, lq = lane >> 4;

  // B DMA source: wave w deposits group w (1KB) of each 8KB B tile
  const char* srcB = (const char*)(wpk + (size_t)nb * 131072 + w * 512 + lane * 8);

  // A gather addresses (bytes), advance 8192/tile
  const int rA = wm * 16 + lrow;
#define CHUNK(r, c) (((r) >> 3) * 64 + ((r) & 7) * 8 + (((c) ^ (r)) & 7))
  u64 aA0 = (u64)(const char*)(apk + (size_t)mb * 131072 + CHUNK(rA, lq) * 8);
  u64 aA1 = (u64)(const char*)(apk + (size_t)mb * 131072 + CHUNK(rA, 4 + lq) * 8);

  // B fragment LDS byte addresses
  unsigned smb = (unsigned)(uintptr_t)(__attribute__((address_space(3))) void*)&sm;
  const int rB0 = wcol * 32 + lrow, rB1 = rB0 + 16;
  unsigned oB00 = smb + CHUNK(rB0, lq) * 16, oB01 = smb + CHUNK(rB0, 4 + lq) * 16;
  unsigned oB10 = smb + CHUNK(rB1, lq) * 16, oB11 = smb + CHUNK(rB1, 4 + lq) * 16;
#undef CHUNK

  f32x4 acc0 = {0.f, 0.f, 0.f, 0.f}, acc1 = {0.f, 0.f, 0.f, 0.f};
  short8 areg[4][2];

  // prologue: tiles 0,1,2 -> issue order per tile: D, Aa, Ab
#pragma unroll
  for (int t = 0; t < 3; ++t) {
    dma16(srcB, &sm.stage[t][w * 512]);
    srcB += 8192;
    GLD16(areg[t][0], aA0); aA0 += 8192;
    GLD16(areg[t][1], aA1); aA1 += 8192;
  }

#define KSTEP(S, PRE, POST, ISSUE)                                          \
  {                                                                         \
    WAITV(PRE);                                                             \
    BAR();                                                                  \
    if (ISSUE) {                                                            \
      dma16(srcB, &sm.stage[(S + 3) & 3][w * 512]);                         \
      srcB += 8192;                                                         \
      GLD16(areg[(S + 3) & 3][0], aA0); aA0 += 8192;                        \
      GLD16(areg[(S + 3) & 3][1], aA1); aA1 += 8192;                        \
    }                                                                       \
    WAITV_TIE2(POST, areg[S][0], areg[S][1]);                               \
    short8 b00, b01, b10, b11;                                              \
    DSR(b00, oB00 + (S) * 8192u); DSR(b10, oB10 + (S) * 8192u);             \
    DSR(b01, oB01 + (S) * 8192u); DSR(b11, oB11 + (S) * 8192u);             \
    LGKM0_TIE4(b00, b01, b10, b11);                                         \
    acc0 = __builtin_amdgcn_mfma_f32_16x16x32_bf16(areg[S][0], b00, acc0, 0, 0, 0); \
    acc1 = __builtin_amdgcn_mfma_f32_16x16x32_bf16(areg[S][0], b10, acc1, 0, 0, 0); \
    acc0 = __builtin_amdgcn_mfma_f32_16x16x32_bf16(areg[S][1], b01, acc0, 0, 0, 0); \
    acc1 = __builtin_amdgcn_mfma_f32_16x16x32_bf16(areg[S][1], b11, acc1, 0, 0, 0); \
  }

  // kt = 0..27 (7 x 4, slots static), then peeled 28..31 with exact tail waits
  for (int i = 0; i < 7; ++i) {
    KSTEP(0, 8, 9, 1)
    KSTEP(1, 8, 9, 1)
    KSTEP(2, 8, 9, 1)
    KSTEP(3, 8, 9, 1)
  }
  KSTEP(0, 8, 9, 1)   // kt=28, issues tile 31
  KSTEP(1, 8, 6, 0)   // kt=29
  KSTEP(2, 5, 3, 0)   // kt=30
  KSTEP(3, 2, 0, 0)   // kt=31
#undef KSTEP

  FULLBAR();  // vmcnt already 0; drain LDS, then overlay sg over stage

  // acc layout (verified): row = m0 + wm*16 + lq*4 + r, gate = wcol*2+nt, hcol = lrow
#pragma unroll
  for (int nt = 0; nt < 2; ++nt) {
    int gate = wcol * 2 + nt;
    int rowb = wm * 16 + lq * 4;
    const f32x4& a = nt ? acc1 : acc0;
#pragma unroll
    for (int r = 0; r < 4; ++r)
      sm.sg[gate * 1088 + (rowb + r) * 17 + lrow] = a[r];
  }
  FULLBAR();

  {
    const int erow = tid >> 3, ehp = (tid & 7) * 2;
    // epilogue-only global loads: issued after all counted VM ops (safe)
    float2 cp = *(const float2*)(c0l + (size_t)(m0 + erow) * 1024 + h0c + ehp);
    float cpa[2] = {cp.x, cp.y};
    float hva[2], cva[2];
#pragma unroll
    for (int e = 0; e < 2; ++e) {
      int hc = ehp + e;
      float gi = sm.sg[0 * 1088 + erow * 17 + hc] + bi[h0c + hc]          + bh[h0c + hc];
      float gf = sm.sg[1 * 1088 + erow * 17 + hc] + bi[1024 + h0c + hc]   + bh[1024 + h0c + hc];
      float gg = sm.sg[2 * 1088 + erow * 17 + hc] + bi[2048 + h0c + hc]   + bh[2048 + h0c + hc];
      float go = sm.sg[3 * 1088 + erow * 17 + hc] + bi[3072 + h0c + hc]   + bh[3072 + h0c + hc];
      float cn = sigm(gf) * cpa[e] + sigm(gi) * tanh_(gg);
      cva[e] = cn;
      hva[e] = sigm(go) * tanh_(cn);
    }
    float2 hv; hv.x = hva[0]; hv.y = hva[1];
    float2 cv; cv.x = cva[0]; cv.y = cva[1];
    *(float2*)(hout + (size_t)(m0 + erow) * 1024 + h0c + ehp) = hv;
    *(float2*)(cout + (size_t)(m0 + erow) * 1024 + h0c + ehp) = cv;
    if (apk_next) {  // packed bf16 h for next layer's A gathers
      int g = erow >> 3;
#pragma unroll
      for (int e = 0; e < 2; ++e) {
        int k = h0c + ehp + e;
        int cc = (k >> 3) & 7, j = k & 7;
        int i = (erow & 7) * 8 + ((cc ^ erow) & 7);
        apk_next[(size_t)mb * 131072 + (size_t)(k >> 6) * 4096 + g * 512 + i * 8 + j] =
            f2bf(hva[e]);
      }
    }
  }
}

extern "C" void kernel_launch(void* const* d_in, const int* in_sizes, int n_in,
                              void* d_out, int out_size, void* d_ws, size_t ws_size,
                              hipStream_t stream) {
  const float* x    = (const float*)d_in[0];
  const float* h0   = (const float*)d_in[1];
  const float* c0   = (const float*)d_in[2];
  const float* w_ih = (const float*)d_in[3];
  const float* w_hh = (const float*)d_in[4];
  const float* b_ih = (const float*)d_in[5];
  const float* b_hh = (const float*)d_in[6];
  float* out = (float*)d_out;

  ushort_t* Wpk = (ushort_t*)d_ws;              // 4 layers x 16 MB
  ushort_t* Apk = Wpk + (size_t)4 * 8388608;    // 4 layers x 1 MB

  pack_w<<<8192, 256, 0, stream>>>(w_ih, w_hh, Wpk);
  pack_a<<<640, 256, 0, stream>>>(x, h0, Apk);

  const size_t BH = (size_t)BATCH * HID;
  for (int l = 0; l < NLAYER; ++l) {
    lstm_fused<<<dim3(64, 4), 512, 0, stream>>>(
        Apk + (size_t)l * 524288, Wpk + (size_t)l * 8388608,
        b_ih + (size_t)l * 4096, b_hh + (size_t)l * 4096,
        c0 + (size_t)l * BH,
        out + (size_t)l * BH, out + (size_t)NLAYER * BH + (size_t)l * BH,
        (l < NLAYER - 1) ? Apk + (size_t)(l + 1) * 524288 : (ushort_t*)nullptr);
  }
}